// Round 7
// baseline (264.421 us; speedup 1.0000x reference)
//
#include <hip/hip_runtime.h>
#include <cmath>

#define NCC 151
#define NRCH 51
#define BDIM 32
#define NOBJ 100
#define DDIM 4096
#define HDIM 1024
#define TDIM (BDIM * NOBJ)   // 3200

typedef __bf16 bf16_t;
typedef __bf16 bf16x8 __attribute__((ext_vector_type(8)));
typedef __bf16 bf16x4 __attribute__((ext_vector_type(4)));
typedef float f32x4 __attribute__((ext_vector_type(4)));

// ---------------------------------------------------------------------------
// bf16 MFMA GEMM (m97 structure): C[M,N] = act(A[M,K] @ Bt[N,K]^T) (+ add)
// 128x128 tile, BK=64, 256 threads = 4 waves (2x2), 16x16x32 MFMA.
// XOR-swizzled LDS (rule #21).
// MODE 0: bijective XCD-chunk swizzle, by-fastest within chunk.
// MODE 1: bz = hwid & 7 (gridDim.z == 8): each XCD owns one K-plane.
// SPLITK>1: block writes bf16 partial to Cout + bz*MN; reduceN finishes.
// ADDBF16: residual add from bf16 buffer, fp32 output (G4).
// ---------------------------------------------------------------------------
template <bool RELU, bool ADDBF16, int SPLITK, int MODE>
__global__ __launch_bounds__(256) void gemm_bf16(
    const bf16_t* __restrict__ A,   // [M][K] row-major
    const bf16_t* __restrict__ Bt,  // [N][K] row-major (pre-transposed weight)
    const bf16_t* __restrict__ add, // bf16 residual when ADDBF16
    void* __restrict__ Cout,        // bf16 [M][N]; fp32 if ADDBF16
    int N, int K, size_t MN) {
  __shared__ __align__(16) bf16_t Asm[128 * 64];
  __shared__ __align__(16) bf16_t Bsm[128 * 64];
  const int tid = threadIdx.x;
  const int lane = tid & 63;
  const int w = tid >> 6;           // wave 0..3
  const int wm = w >> 1, wn = w & 1;

  const int nx = gridDim.x, ny = gridDim.y, nz = gridDim.z;
  const int h = blockIdx.x + nx * (blockIdx.y + ny * blockIdx.z);
  int bx, by, bz;
  if (MODE == 1) {
    bz = h & 7;               // XCD k <-> K-plane k
    const int s = h >> 3;
    by = s % ny;
    bx = s / ny;
  } else {
    const int nwg = nx * ny * nz;  // must be % 8 == 0
    const int q = nwg >> 3;
    const int lin = (h & 7) * q + (h >> 3);
    by = lin % ny;
    const int r = lin / ny;
    bx = r % nx;
    bz = r / nx;
  }

  const int bm = by * 128, bn = bx * 128;
  const int lr = lane & 15;         // fragment row
  const int lk = lane >> 4;         // k sub-slot (0..3)

  int kBeg = 0, kEnd = K;
  if (SPLITK > 1) {
    const int chunk = (((K / 64) + SPLITK - 1) / SPLITK) * 64;
    kBeg = bz * chunk;
    kEnd = min(K, kBeg + chunk);
  }

  f32x4 acc[4][4];
#pragma unroll
  for (int m = 0; m < 4; ++m)
#pragma unroll
    for (int n = 0; n < 4; ++n) acc[m][n] = (f32x4){0.f, 0.f, 0.f, 0.f};

  const int srow = tid >> 3;   // staging row within 32-row group
  const int sslot = tid & 7;   // staging 16B slot within row

  char* ldsA = (char*)Asm;
  char* ldsB = (char*)Bsm;

  for (int kt = kBeg; kt < kEnd; kt += 64) {
    __syncthreads();
#pragma unroll
    for (int i = 0; i < 4; ++i) {
      const int row = i * 32 + srow;
      const int kc = sslot ^ (row & 7);
      const bf16_t* ga = A + (size_t)(bm + row) * K + kt + kc * 8;
      const bf16_t* gb = Bt + (size_t)(bn + row) * K + kt + kc * 8;
      __builtin_amdgcn_global_load_lds(
          (const __attribute__((address_space(1))) void*)ga,
          (__attribute__((address_space(3))) void*)(ldsA + i * 4096 + w * 1024),
          16, 0, 0);
      __builtin_amdgcn_global_load_lds(
          (const __attribute__((address_space(1))) void*)gb,
          (__attribute__((address_space(3))) void*)(ldsB + i * 4096 + w * 1024),
          16, 0, 0);
    }
    __syncthreads();

    bf16x8 af[4][2], bfr[4][2];
#pragma unroll
    for (int m = 0; m < 4; ++m) {
      const int row = wm * 64 + m * 16 + lr;
#pragma unroll
      for (int kk = 0; kk < 2; ++kk) {
        const int slot = kk * 4 + lk;
        af[m][kk] =
            *(const bf16x8*)(ldsA + row * 128 + ((slot ^ (lr & 7)) << 4));
      }
    }
#pragma unroll
    for (int n = 0; n < 4; ++n) {
      const int row = wn * 64 + n * 16 + lr;
#pragma unroll
      for (int kk = 0; kk < 2; ++kk) {
        const int slot = kk * 4 + lk;
        bfr[n][kk] =
            *(const bf16x8*)(ldsB + row * 128 + ((slot ^ (lr & 7)) << 4));
      }
    }
#pragma unroll
    for (int m = 0; m < 4; ++m)
#pragma unroll
      for (int n = 0; n < 4; ++n) {
        acc[m][n] = __builtin_amdgcn_mfma_f32_16x16x32_bf16(
            af[m][0], bfr[n][0], acc[m][n], 0, 0, 0);
        acc[m][n] = __builtin_amdgcn_mfma_f32_16x16x32_bf16(
            af[m][1], bfr[n][1], acc[m][n], 0, 0, 0);
      }
  }

  const int or0 = bm + wm * 64 + lk * 4;
  const int oc0 = bn + wn * 64 + lr;
#pragma unroll
  for (int m = 0; m < 4; ++m)
#pragma unroll
    for (int n = 0; n < 4; ++n)
#pragma unroll
      for (int r = 0; r < 4; ++r) {
        float v = acc[m][n][r];
        const size_t off = (size_t)(or0 + m * 16 + r) * N + (oc0 + n * 16);
        if (SPLITK > 1) {
          ((bf16_t*)Cout)[bz * MN + off] = (bf16_t)v;  // bf16 partial
        } else {
          if (RELU) v = fmaxf(v, 0.f);
          if (ADDBF16)
            ((float*)Cout)[off] = v + (float)add[off];
          else
            ((bf16_t*)Cout)[off] = (bf16_t)v;
        }
      }
}

// reduce NPART bf16 partials -> relu -> bf16
template <int NPART>
__global__ __launch_bounds__(256) void reduceN_kernel(
    const bf16_t* __restrict__ p, bf16_t* __restrict__ out, int n8,
    size_t MN) {
  int i = blockIdx.x * 256 + threadIdx.x;
  if (i >= n8) return;
  float s[8] = {};
#pragma unroll
  for (int z = 0; z < NPART; ++z) {
    bf16x8 v = *(const bf16x8*)(p + z * MN + (size_t)i * 8);
#pragma unroll
    for (int j = 0; j < 8; ++j) s[j] += (float)v[j];
  }
  bf16x8 o;
#pragma unroll
  for (int j = 0; j < 8; ++j) o[j] = (bf16_t)fmaxf(s[j], 0.f);
  *(bf16x8*)(out + (size_t)i * 8) = o;
}

// ---------------------------------------------------------------------------
__global__ __launch_bounds__(256) void cvt_bf16_kernel(
    const float* __restrict__ in, bf16_t* __restrict__ out, int n4) {
  int i = blockIdx.x * 256 + threadIdx.x;
  if (i >= n4) return;
  float4 v = ((const float4*)in)[i];
  bf16x4 o = {(bf16_t)v.x, (bf16_t)v.y, (bf16_t)v.z, (bf16_t)v.w};
  ((bf16x4*)out)[i] = o;
}

// ---------------------------------------------------------------------------
// W[K][N] fp32 -> Wt[N][K] bf16, 32x32 LDS tile transpose
// ---------------------------------------------------------------------------
__global__ __launch_bounds__(256) void transT_kernel(
    const float* __restrict__ in, bf16_t* __restrict__ out, int K, int N) {
  __shared__ float t[32][33];
  const int n0 = blockIdx.x * 32, k0 = blockIdx.y * 32;
  const int tx = threadIdx.x & 31, ty = threadIdx.x >> 5;  // 32 x 8
#pragma unroll
  for (int i = 0; i < 4; ++i)
    t[ty + i * 8][tx] = in[(size_t)(k0 + ty + i * 8) * N + n0 + tx];
  __syncthreads();
#pragma unroll
  for (int i = 0; i < 4; ++i)
    out[(size_t)(n0 + ty + i * 8) * K + k0 + tx] = (bf16_t)t[tx][ty + i * 8];
}

// ---------------------------------------------------------------------------
// Conv chain, fully collapsed (R7):
//  femb1[p][d1][c2] = sum_ci w1[c2,ci,d1]*femb[p][ci]          (per-pair)
//  femb2[p][d2][d1] = sum_c2 w23[d2][c2]*femb1[p][d1][c2]      (81/pair)
//  femb2s[p][e]     = sum_{d1+d2=e} femb2[p][d2][d1]           (25/pair)
//  adj(p) = tanh( sum_e femb2s[pix(p+e)][e]  -  rim corrections )
// Rim correction subtracts (d2,d1) terms whose intermediate p+d2 is
// off-grid (conv1 output zero-padding) — only border pixels need it.
// Exact reordering of the reference fp32 math.
// ---------------------------------------------------------------------------
__global__ __launch_bounds__(256) void prep_w1r_kernel(
    const float* __restrict__ w1, float* __restrict__ w1r) {
  int idx = blockIdx.x * 256 + threadIdx.x;
  if (idx >= NRCH * 90) return;
  int ci = idx / 90, r = idx % 90, k9 = r / 10, co = r % 10;
  w1r[idx] = w1[((co * NRCH + ci) * 3 + k9 / 3) * 3 + (k9 % 3)];
}

__global__ __launch_bounds__(128) void prep_w23_kernel(
    const float* __restrict__ w2, const float* __restrict__ w3,
    float* __restrict__ w23) {
  int t = threadIdx.x;
  if (t >= 90) return;
  int k9 = t / 10, c2 = t % 10;
  float acc = 0.f;
#pragma unroll
  for (int c3 = 0; c3 < 5; ++c3)
    acc += w3[c3] * w2[((c3 * 10 + c2) * 3 + k9 / 3) * 3 + (k9 % 3)];
  w23[t] = acc;
}

__global__ __launch_bounds__(256) void pidx_kernel(
    const int* __restrict__ preds, int* __restrict__ pidx) {
  int idx = blockIdx.x * 256 + threadIdx.x;
  if (idx >= BDIM * NOBJ * NOBJ) return;
  int j = idx % NOBJ;
  int i = (idx / NOBJ) % NOBJ;
  int b = idx / (NOBJ * NOBJ);
  pidx[idx] = preds[b * NOBJ + i] * NCC + preds[b * NOBJ + j];
}

__global__ __launch_bounds__(128) void femb1_kernel(
    const float* __restrict__ femb, const float* __restrict__ w1r,
    float* __restrict__ femb1) {
  __shared__ float row[NRCH];
  const int p = blockIdx.x;
  if (threadIdx.x < NRCH)
    row[threadIdx.x] = femb[(size_t)p * NRCH + threadIdx.x];
  __syncthreads();
  const int t = threadIdx.x;
  if (t >= 90) return;
  float acc = 0.f;
#pragma unroll
  for (int ci = 0; ci < NRCH; ++ci) acc += row[ci] * w1r[ci * 90 + t];
  femb1[((size_t)p * 9 + t / 10) * 12 + (t % 10)] = acc;
}

// per pair: build femb2 (81) and femb2s (25)
__global__ __launch_bounds__(128) void femb2_kernel(
    const float* __restrict__ femb1, const float* __restrict__ w23,
    float* __restrict__ femb2, float* __restrict__ femb2s) {
  __shared__ float f1[90];  // [d1][c]
  __shared__ float w[90];   // [d2][c]
  __shared__ float g[81];   // [d2][d1]
  const int p = blockIdx.x;
  const int t = threadIdx.x;
  if (t < 90) {
    f1[t] = femb1[((size_t)p * 9 + t / 10) * 12 + (t % 10)];
    w[t] = w23[t];
  }
  __syncthreads();
  if (t < 81) {
    int d2 = t / 9, d1 = t % 9;
    float a = 0.f;
#pragma unroll
    for (int c = 0; c < 10; ++c) a += w[d2 * 10 + c] * f1[d1 * 10 + c];
    g[t] = a;
    femb2[(size_t)p * 81 + t] = a;
  }
  __syncthreads();
  if (t < 25) {
    int eh = t / 5 - 2, ew = t % 5 - 2;
    float s = 0.f;
#pragma unroll
    for (int d2h = -1; d2h <= 1; ++d2h)
#pragma unroll
      for (int d2w = -1; d2w <= 1; ++d2w) {
        int d1h = eh - d2h, d1w = ew - d2w;
        if (d1h < -1 || d1h > 1 || d1w < -1 || d1w > 1) continue;
        s += g[((d2h + 1) * 3 + d2w + 1) * 9 + (d1h + 1) * 3 + (d1w + 1)];
      }
    femb2s[(size_t)p * 25 + t] = s;
  }
}

// adj[b][i][j] = tanh( 5x5 gather-sum of femb2s - border corrections )
__global__ __launch_bounds__(256) void adj25_kernel(
    const int* __restrict__ pidx, const float* __restrict__ f2s,
    const float* __restrict__ f2, float* __restrict__ adj) {
  int idx = blockIdx.x * 256 + threadIdx.x;
  if (idx >= BDIM * NOBJ * NOBJ) return;
  int j = idx % NOBJ;
  int i = (idx / NOBJ) % NOBJ;
  int b = idx / (NOBJ * NOBJ);
  const int* pb = pidx + b * NOBJ * NOBJ;
  float acc = 0.f;
#pragma unroll
  for (int eh = -2; eh <= 2; ++eh) {
    int ii = i + eh;
    if (ii < 0 || ii >= NOBJ) continue;
#pragma unroll
    for (int ew = -2; ew <= 2; ++ew) {
      int jj = j + ew;
      if (jj < 0 || jj >= NOBJ) continue;
      acc += f2s[(size_t)pb[ii * NOBJ + jj] * 25 + (eh + 2) * 5 + (ew + 2)];
    }
  }
  if (i < 1 || i > NOBJ - 2 || j < 1 || j > NOBJ - 2) {
    for (int d2h = -1; d2h <= 1; ++d2h)
      for (int d2w = -1; d2w <= 1; ++d2w) {
        int qi = i + d2h, qj = j + d2w;
        if (qi >= 0 && qi < NOBJ && qj >= 0 && qj < NOBJ) continue;
        for (int d1h = -1; d1h <= 1; ++d1h)
          for (int d1w = -1; d1w <= 1; ++d1w) {
            int ti = qi + d1h, tj = qj + d1w;
            if (ti < 0 || ti >= NOBJ || tj < 0 || tj >= NOBJ) continue;
            acc -= f2[(size_t)pb[ti * NOBJ + tj] * 81 +
                      ((d2h + 1) * 3 + d2w + 1) * 9 + (d1h + 1) * 3 +
                      (d1w + 1)];
          }
      }
  }
  adj[idx] = tanhf(acc);
}

// ---------------------------------------------------------------------------
// einsum via MFMA: ofl_u[b] = adj[b] (100x100) @ u1[b] (100x1024)
// (see R4 notes; swizzled LDS transpose-on-stage, K padded to 128, zeroed)
// ---------------------------------------------------------------------------
__global__ __launch_bounds__(256) void einsum_mfma_kernel(
    const float* __restrict__ adj,    // [32][100][100]
    const bf16_t* __restrict__ u1,    // [3200][1024]
    bf16_t* __restrict__ ofl) {       // [3200][1024]
  __shared__ __align__(16) bf16_t As[128 * 128];  // [n-row][k=m] swizzled
  __shared__ __align__(16) bf16_t Us[128 * 128];  // [h-col][k=m] swizzled
  const int b = blockIdx.y;
  const int h0 = blockIdx.x * 128;
  const int tid = threadIdx.x, lane = tid & 63, w = tid >> 6;
  const int wm = w >> 1, wn = w & 1;
  const int lr = lane & 15, lk = lane >> 4;

  {
    f32x4 z = {0.f, 0.f, 0.f, 0.f};
#pragma unroll
    for (int i = 0; i < 8; ++i) ((f32x4*)As)[tid + i * 256] = z;
#pragma unroll
    for (int i = 0; i < 8; ++i) ((f32x4*)Us)[tid + i * 256] = z;
  }
  __syncthreads();

  const float* ab = adj + (size_t)b * 10000;
#pragma unroll
  for (int i = 0; i < 10; ++i) {
    int idx = tid + i * 256;
    if (idx < 2500) {
      int row = idx / 25, kc = idx % 25;
      f32x4 v = ((const f32x4*)ab)[idx];
      bf16x4 o = {(bf16_t)v[0], (bf16_t)v[1], (bf16_t)v[2], (bf16_t)v[3]};
      int slot = kc >> 1;
      *(bf16x4*)((char*)As + row * 256 + ((slot ^ (row & 7)) << 4) +
                 (kc & 1) * 8) = o;
    }
  }

  const bf16_t* ub = u1 + (size_t)b * 100 * HDIM + h0;
#pragma unroll
  for (int i = 0; i < 7; ++i) {
    int idx = tid + i * 256;
    if (idx < 1600) {
      int hc = idx / 100, m = idx % 100;
      bf16x8 v = *(const bf16x8*)(ub + (size_t)m * HDIM + hc * 8);
      int slot = m >> 3, mr = m & 7;
#pragma unroll
      for (int j = 0; j < 8; ++j) {
        int h = hc * 8 + j;
        *((bf16_t*)((char*)Us + h * 256 + ((slot ^ (h & 7)) << 4) + mr * 2)) =
            v[j];
      }
    }
  }
  __syncthreads();

  f32x4 acc[4][4];
#pragma unroll
  for (int m = 0; m < 4; ++m)
#pragma unroll
    for (int n = 0; n < 4; ++n) acc[m][n] = (f32x4){0.f, 0.f, 0.f, 0.f};

#pragma unroll
  for (int ks = 0; ks < 4; ++ks) {
    bf16x8 a[4], u[4];
#pragma unroll
    for (int m = 0; m < 4; ++m) {
      int row = wm * 64 + m * 16 + lr;
      int slot = ks * 4 + lk;
      a[m] = *(const bf16x8*)((char*)As + row * 256 + ((slot ^ (lr & 7)) << 4));
    }
#pragma unroll
    for (int n = 0; n < 4; ++n) {
      int row = wn * 64 + n * 16 + lr;
      int slot = ks * 4 + lk;
      u[n] = *(const bf16x8*)((char*)Us + row * 256 + ((slot ^ (lr & 7)) << 4));
    }
#pragma unroll
    for (int m = 0; m < 4; ++m)
#pragma unroll
      for (int n = 0; n < 4; ++n)
        acc[m][n] = __builtin_amdgcn_mfma_f32_16x16x32_bf16(a[m], u[n],
                                                            acc[m][n], 0, 0, 0);
  }

  const int or0 = wm * 64 + lk * 4;
  const int oc0 = h0 + wn * 64 + lr;
#pragma unroll
  for (int m = 0; m < 4; ++m)
#pragma unroll
    for (int n = 0; n < 4; ++n)
#pragma unroll
      for (int r = 0; r < 4; ++r) {
        int row = or0 + m * 16 + r;
        if (row < 100)
          ofl[((size_t)b * 100 + row) * HDIM + oc0 + n * 16] =
              (bf16_t)acc[m][n][r];
      }
}

// ---------------------------------------------------------------------------
extern "C" void kernel_launch(void* const* d_in, const int* in_sizes, int n_in,
                              void* d_out, int out_size, void* d_ws,
                              size_t ws_size, hipStream_t stream) {
  const float* enc = (const float*)d_in[0];
  const float* W_comp = (const float*)d_in[1];
  const float* W_ou1 = (const float*)d_in[2];
  const float* W_ofc = (const float*)d_in[3];
  const float* W_dec = (const float*)d_in[4];
  const float* conv1w = (const float*)d_in[5];
  const float* conv2w = (const float*)d_in[6];
  const float* conv3w = (const float*)d_in[7];
  const float* femb = (const float*)d_in[8];
  const int* preds = (const int*)d_in[9];
  float* out = (float*)d_out;
  char* wsb = (char*)d_ws;

  const size_t MN = (size_t)TDIM * HDIM;  // 3,276,800

  // workspace (bytes), peak 93.6MB (ws >= 112MB proven in R1).
  // encb stays LIVE until G4 (bf16 residual). Timeline:
  //  part8 [41.16M,93.59M) dead after reduce8; Wou1T dead after G2;
  //  w1r/w23/femb1 dead after femb2_kernel; femb2/femb2s dead after adj25;
  //  phase-C buffers overlay WcompT/comp/part8-head/w1r..femb1 (all dead).
  bf16_t* encb   = (bf16_t*)(wsb + 0);           // 26,214,400 (LIVE to G4)
  bf16_t* WcompT = (bf16_t*)(wsb + 26214400);    //  8,388,608
  bf16_t* comp   = (bf16_t*)(wsb + 34603008);    //  6,553,600
  bf16_t* part8  = (bf16_t*)(wsb + 41156608);    // 52,428,800 (ends 93.59M)
  bf16_t* Wou1T  = (bf16_t*)(wsb + 41156608);    //  2,097,152 (after reduce8)
  float*  w1r    = (float*)(wsb + 43253760);     //     18,360
  float*  w23    = (float*)(wsb + 43272128);     //        360
  float*  femb1  = (float*)(wsb + 43272512);     //  9,850,032 (ends 53.12M)
  int*    pidx   = (int*)(wsb + 53122560);       //  1,280,000 (ends 54.40M)
  float*  femb2  = (float*)(wsb + 54402560);     //  7,387,524 (ends 61.79M)
  float*  femb2s = (float*)(wsb + 61790208);     //  2,280,100 (ends 64.07M)
  bf16_t* obj_u1 = (bf16_t*)(wsb + 69762560);    //  6,553,600
  float*  adj    = (float*)(wsb + 76316160);     //  1,280,000 (ends 77.6M)
  // phase C
  bf16_t* ofl_u  = (bf16_t*)(wsb + 26214400);    //  6,553,600 (over WcompT)
  bf16_t* WofcT  = (bf16_t*)(wsb + 32768000);    //  2,097,152
  bf16_t* u_m    = (bf16_t*)(wsb + 34865152);    //  6,553,600 (ends 41.42M)
  bf16_t* WdecT  = (bf16_t*)(wsb + 41418752);    //  8,388,608 (ends 49.81M)

  const int n8 = (int)(MN / 8);  // 409,600 -> 1600 blocks for reduceN

  // --- conversions for GEMM1 ---
  cvt_bf16_kernel<<<(TDIM * DDIM / 4 + 255) / 256, 256, 0, stream>>>(
      enc, encb, TDIM * DDIM / 4);
  transT_kernel<<<dim3(HDIM / 32, DDIM / 32), 256, 0, stream>>>(
      W_comp, WcompT, DDIM, HDIM);

  // 1. comp = relu(enc @ W_comp)  M=3200 N=1024 K=4096, split-K=8, XCD-plane
  gemm_bf16<false, false, 8, 1>
      <<<dim3(HDIM / 128, TDIM / 128, 8), 256, 0, stream>>>(
          encb, WcompT, nullptr, part8, HDIM, DDIM, MN);
  reduceN_kernel<8><<<n8 / 256, 256, 0, stream>>>(part8, comp, n8, MN);

  // 2. obj_u1 = relu(comp @ W_ou1) M=3200 N=1024 K=1024
  transT_kernel<<<dim3(HDIM / 32, HDIM / 32), 256, 0, stream>>>(
      W_ou1, Wou1T, HDIM, HDIM);
  gemm_bf16<true, false, 1, 0>
      <<<dim3(HDIM / 128, TDIM / 128), 256, 0, stream>>>(
          comp, Wou1T, nullptr, obj_u1, HDIM, HDIM, MN);

  // 3. collapsed conv-chain precomputes
  prep_w1r_kernel<<<(NRCH * 90 + 255) / 256, 256, 0, stream>>>(conv1w, w1r);
  prep_w23_kernel<<<1, 128, 0, stream>>>(conv2w, conv3w, w23);
  pidx_kernel<<<(BDIM * NOBJ * NOBJ + 255) / 256, 256, 0, stream>>>(preds,
                                                                    pidx);
  femb1_kernel<<<NCC * NCC, 128, 0, stream>>>(femb, w1r, femb1);
  femb2_kernel<<<NCC * NCC, 128, 0, stream>>>(femb1, w23, femb2, femb2s);

  // 4. adjacency in one gather pass
  adj25_kernel<<<(BDIM * NOBJ * NOBJ + 255) / 256, 256, 0, stream>>>(
      pidx, femb2s, femb2, adj);

  // conversions for GEMM3/4
  transT_kernel<<<dim3(HDIM / 32, HDIM / 32), 256, 0, stream>>>(
      W_ofc, WofcT, HDIM, HDIM);
  transT_kernel<<<dim3(DDIM / 32, HDIM / 32), 256, 0, stream>>>(
      W_dec, WdecT, HDIM, DDIM);

  // 7. einsum via MFMA -> ofl_u (bf16)
  einsum_mfma_kernel<<<dim3(HDIM / 128, BDIM), 256, 0, stream>>>(adj, obj_u1,
                                                                 ofl_u);

  // 8. u_m = relu(ofl_u @ W_ofc)  M=3200 N=1024 K=1024
  gemm_bf16<true, false, 1, 0>
      <<<dim3(HDIM / 128, TDIM / 128), 256, 0, stream>>>(
          ofl_u, WofcT, nullptr, u_m, HDIM, HDIM, MN);

  // 9. out = relu(u_m @ W_dec) + enc(bf16)  M=3200 N=4096 K=1024 (fp32 out)
  gemm_bf16<true, true, 1, 0>
      <<<dim3(DDIM / 128, TDIM / 128), 256, 0, stream>>>(
          u_m, WdecT, encb, out, DDIM, HDIM, MN);
}

// Round 8
// 249.164 us; speedup vs baseline: 1.0612x; 1.0612x over previous
//
#include <hip/hip_runtime.h>
#include <cmath>

#define NCC 151
#define NRCH 51
#define BDIM 32
#define NOBJ 100
#define DDIM 4096
#define HDIM 1024
#define TDIM (BDIM * NOBJ)   // 3200

typedef __bf16 bf16_t;
typedef __bf16 bf16x8 __attribute__((ext_vector_type(8)));
typedef __bf16 bf16x4 __attribute__((ext_vector_type(4)));
typedef float f32x4 __attribute__((ext_vector_type(4)));

// ---------------------------------------------------------------------------
// bf16 MFMA GEMM (m97 structure): C[M,N] = act(A[M,K] @ Bt[N,K]^T) (+ add)
// 128x128 tile, BK=64, 256 threads = 4 waves (2x2), 16x16x32 MFMA.
// XOR-swizzled LDS (rule #21).
// MODE 0: bijective XCD-chunk swizzle, by-fastest within chunk.
// MODE 1: bz = hwid & 7 (gridDim.z == 8): each XCD owns one K-plane.
// MODE 3 (G1, SPLITK=4, grid 832 flat): XCD-pair owns one K=1024 plane;
//   within an XCD, 5-row A-chunks swept bx-fastest so A-chunk (1.25MB) +
//   B-plane (2MB) stay L2-resident; halves split by rows (13/12), 8 idle
//   blocks on odd XCDs.
// SPLITK>1: block writes bf16 partial to Cout + bz*MN; reduceN finishes.
// ADDBF16: residual add from bf16 buffer, fp32 output (G4).
// ---------------------------------------------------------------------------
template <bool RELU, bool ADDBF16, int SPLITK, int MODE>
__global__ __launch_bounds__(256) void gemm_bf16(
    const bf16_t* __restrict__ A,   // [M][K] row-major
    const bf16_t* __restrict__ Bt,  // [N][K] row-major (pre-transposed weight)
    const bf16_t* __restrict__ add, // bf16 residual when ADDBF16
    void* __restrict__ Cout,        // bf16 [M][N]; fp32 if ADDBF16
    int N, int K, size_t MN) {
  __shared__ __align__(16) bf16_t Asm[128 * 64];
  __shared__ __align__(16) bf16_t Bsm[128 * 64];
  const int tid = threadIdx.x;
  const int lane = tid & 63;
  const int w = tid >> 6;           // wave 0..3
  const int wm = w >> 1, wn = w & 1;

  const int nx = gridDim.x, ny = gridDim.y, nz = gridDim.z;
  const int h = blockIdx.x + nx * (blockIdx.y + ny * blockIdx.z);
  int bx, by, bz;
  if (MODE == 1) {
    bz = h & 7;               // XCD k <-> K-plane k
    const int s = h >> 3;
    by = s % ny;
    bx = s / ny;
  } else if (MODE == 3) {
    const int xcd = h & 7, s = h >> 3;   // s in [0,104)
    bz = xcd >> 1;
    const int half = xcd & 1;
    if (half == 1 && s >= 96) return;    // idle pad blocks
    const int c = s / 40;
    if (c < 2) {
      const int within = s % 40;
      bx = within / 5;
      by = (half ? 13 : 0) + c * 5 + within % 5;
    } else if (half == 0) {
      const int w2 = s - 80;             // [0,24)
      bx = w2 / 3;
      by = 10 + w2 % 3;
    } else {
      const int w2 = s - 80;             // [0,16)
      bx = w2 / 2;
      by = 23 + w2 % 2;
    }
  } else {
    const int nwg = nx * ny * nz;  // must be % 8 == 0
    const int q = nwg >> 3;
    const int lin = (h & 7) * q + (h >> 3);
    by = lin % ny;
    const int r = lin / ny;
    bx = r % nx;
    bz = r / nx;
  }

  const int bm = by * 128, bn = bx * 128;
  const int lr = lane & 15;         // fragment row
  const int lk = lane >> 4;         // k sub-slot (0..3)

  int kBeg = 0, kEnd = K;
  if (SPLITK > 1) {
    const int chunk = (((K / 64) + SPLITK - 1) / SPLITK) * 64;
    kBeg = bz * chunk;
    kEnd = min(K, kBeg + chunk);
  }

  f32x4 acc[4][4];
#pragma unroll
  for (int m = 0; m < 4; ++m)
#pragma unroll
    for (int n = 0; n < 4; ++n) acc[m][n] = (f32x4){0.f, 0.f, 0.f, 0.f};

  const int srow = tid >> 3;   // staging row within 32-row group
  const int sslot = tid & 7;   // staging 16B slot within row

  char* ldsA = (char*)Asm;
  char* ldsB = (char*)Bsm;

  for (int kt = kBeg; kt < kEnd; kt += 64) {
    __syncthreads();
#pragma unroll
    for (int i = 0; i < 4; ++i) {
      const int row = i * 32 + srow;
      const int kc = sslot ^ (row & 7);
      const bf16_t* ga = A + (size_t)(bm + row) * K + kt + kc * 8;
      const bf16_t* gb = Bt + (size_t)(bn + row) * K + kt + kc * 8;
      __builtin_amdgcn_global_load_lds(
          (const __attribute__((address_space(1))) void*)ga,
          (__attribute__((address_space(3))) void*)(ldsA + i * 4096 + w * 1024),
          16, 0, 0);
      __builtin_amdgcn_global_load_lds(
          (const __attribute__((address_space(1))) void*)gb,
          (__attribute__((address_space(3))) void*)(ldsB + i * 4096 + w * 1024),
          16, 0, 0);
    }
    __syncthreads();

    bf16x8 af[4][2], bfr[4][2];
#pragma unroll
    for (int m = 0; m < 4; ++m) {
      const int row = wm * 64 + m * 16 + lr;
#pragma unroll
      for (int kk = 0; kk < 2; ++kk) {
        const int slot = kk * 4 + lk;
        af[m][kk] =
            *(const bf16x8*)(ldsA + row * 128 + ((slot ^ (lr & 7)) << 4));
      }
    }
#pragma unroll
    for (int n = 0; n < 4; ++n) {
      const int row = wn * 64 + n * 16 + lr;
#pragma unroll
      for (int kk = 0; kk < 2; ++kk) {
        const int slot = kk * 4 + lk;
        bfr[n][kk] =
            *(const bf16x8*)(ldsB + row * 128 + ((slot ^ (lr & 7)) << 4));
      }
    }
#pragma unroll
    for (int m = 0; m < 4; ++m)
#pragma unroll
      for (int n = 0; n < 4; ++n) {
        acc[m][n] = __builtin_amdgcn_mfma_f32_16x16x32_bf16(
            af[m][0], bfr[n][0], acc[m][n], 0, 0, 0);
        acc[m][n] = __builtin_amdgcn_mfma_f32_16x16x32_bf16(
            af[m][1], bfr[n][1], acc[m][n], 0, 0, 0);
      }
  }

  const int or0 = bm + wm * 64 + lk * 4;
  const int oc0 = bn + wn * 64 + lr;
#pragma unroll
  for (int m = 0; m < 4; ++m)
#pragma unroll
    for (int n = 0; n < 4; ++n)
#pragma unroll
      for (int r = 0; r < 4; ++r) {
        float v = acc[m][n][r];
        const size_t off = (size_t)(or0 + m * 16 + r) * N + (oc0 + n * 16);
        if (SPLITK > 1) {
          ((bf16_t*)Cout)[bz * MN + off] = (bf16_t)v;  // bf16 partial
        } else {
          if (RELU) v = fmaxf(v, 0.f);
          if (ADDBF16)
            ((float*)Cout)[off] = v + (float)add[off];
          else
            ((bf16_t*)Cout)[off] = (bf16_t)v;
        }
      }
}

// reduce NPART bf16 partials -> relu -> bf16
template <int NPART>
__global__ __launch_bounds__(256) void reduceN_kernel(
    const bf16_t* __restrict__ p, bf16_t* __restrict__ out, int n8,
    size_t MN) {
  int i = blockIdx.x * 256 + threadIdx.x;
  if (i >= n8) return;
  float s[8] = {};
#pragma unroll
  for (int z = 0; z < NPART; ++z) {
    bf16x8 v = *(const bf16x8*)(p + z * MN + (size_t)i * 8);
#pragma unroll
    for (int j = 0; j < 8; ++j) s[j] += (float)v[j];
  }
  bf16x8 o;
#pragma unroll
  for (int j = 0; j < 8; ++j) o[j] = (bf16_t)fmaxf(s[j], 0.f);
  *(bf16x8*)(out + (size_t)i * 8) = o;
}

// ---------------------------------------------------------------------------
__global__ __launch_bounds__(256) void cvt_bf16_kernel(
    const float* __restrict__ in, bf16_t* __restrict__ out, int n4) {
  int i = blockIdx.x * 256 + threadIdx.x;
  if (i >= n4) return;
  float4 v = ((const float4*)in)[i];
  bf16x4 o = {(bf16_t)v.x, (bf16_t)v.y, (bf16_t)v.z, (bf16_t)v.w};
  ((bf16x4*)out)[i] = o;
}

// ---------------------------------------------------------------------------
// W[K][N] fp32 -> Wt[N][K] bf16, 32x32 LDS tile transpose
// ---------------------------------------------------------------------------
__global__ __launch_bounds__(256) void transT_kernel(
    const float* __restrict__ in, bf16_t* __restrict__ out, int K, int N) {
  __shared__ float t[32][33];
  const int n0 = blockIdx.x * 32, k0 = blockIdx.y * 32;
  const int tx = threadIdx.x & 31, ty = threadIdx.x >> 5;  // 32 x 8
#pragma unroll
  for (int i = 0; i < 4; ++i)
    t[ty + i * 8][tx] = in[(size_t)(k0 + ty + i * 8) * N + n0 + tx];
  __syncthreads();
#pragma unroll
  for (int i = 0; i < 4; ++i)
    out[(size_t)(n0 + ty + i * 8) * K + k0 + tx] = (bf16_t)t[tx][ty + i * 8];
}

// ---------------------------------------------------------------------------
// Conv chain (R5 structure — algebraic conv1 projection + fused conv2/3;
// R7's further collapse to adj25 measured SLOWER, reverted)
// ---------------------------------------------------------------------------
__global__ __launch_bounds__(256) void prep_w1r_kernel(
    const float* __restrict__ w1, float* __restrict__ w1r) {
  int idx = blockIdx.x * 256 + threadIdx.x;
  if (idx >= NRCH * 90) return;
  int ci = idx / 90, r = idx % 90, k9 = r / 10, co = r % 10;
  w1r[idx] = w1[((co * NRCH + ci) * 3 + k9 / 3) * 3 + (k9 % 3)];
}

__global__ __launch_bounds__(128) void prep_w23_kernel(
    const float* __restrict__ w2, const float* __restrict__ w3,
    float* __restrict__ w23) {
  int t = threadIdx.x;
  if (t >= 90) return;
  int k9 = t / 10, c2 = t % 10;
  float acc = 0.f;
#pragma unroll
  for (int c3 = 0; c3 < 5; ++c3)
    acc += w3[c3] * w2[((c3 * 10 + c2) * 3 + k9 / 3) * 3 + (k9 % 3)];
  w23[t] = acc;
}

__global__ __launch_bounds__(256) void pidx_kernel(
    const int* __restrict__ preds, int* __restrict__ pidx) {
  int idx = blockIdx.x * 256 + threadIdx.x;
  if (idx >= BDIM * NOBJ * NOBJ) return;
  int j = idx % NOBJ;
  int i = (idx / NOBJ) % NOBJ;
  int b = idx / (NOBJ * NOBJ);
  pidx[idx] = preds[b * NOBJ + i] * NCC + preds[b * NOBJ + j];
}

__global__ __launch_bounds__(128) void femb1_kernel(
    const float* __restrict__ femb, const float* __restrict__ w1r,
    float* __restrict__ femb1) {
  __shared__ float row[NRCH];
  const int p = blockIdx.x;
  if (threadIdx.x < NRCH)
    row[threadIdx.x] = femb[(size_t)p * NRCH + threadIdx.x];
  __syncthreads();
  const int t = threadIdx.x;
  if (t >= 90) return;
  float acc = 0.f;
#pragma unroll
  for (int ci = 0; ci < NRCH; ++ci) acc += row[ci] * w1r[ci * 90 + t];
  femb1[((size_t)p * 9 + t / 10) * 12 + (t % 10)] = acc;
}

__global__ __launch_bounds__(256) void conv1g_kernel(
    const int* __restrict__ pidx, const float* __restrict__ femb1,
    float* __restrict__ x1) {
  int idx = blockIdx.x * 256 + threadIdx.x;
  if (idx >= BDIM * NOBJ * NOBJ) return;
  int j = idx % NOBJ;
  int i = (idx / NOBJ) % NOBJ;
  int b = idx / (NOBJ * NOBJ);
  f32x4 a0 = {0.f, 0.f, 0.f, 0.f}, a1 = a0, a2 = a0;
  const int* pb = pidx + b * NOBJ * NOBJ;
#pragma unroll
  for (int kh = 0; kh < 3; ++kh) {
    int ii = i + kh - 1;
    if (ii < 0 || ii >= NOBJ) continue;
#pragma unroll
    for (int kw = 0; kw < 3; ++kw) {
      int jj = j + kw - 1;
      if (jj < 0 || jj >= NOBJ) continue;
      int p = pb[ii * NOBJ + jj];
      const f32x4* f =
          (const f32x4*)(femb1 + ((size_t)p * 9 + kh * 3 + kw) * 12);
      a0 += f[0];
      a1 += f[1];
      a2 += f[2];
    }
  }
  f32x4* o = (f32x4*)(x1 + (size_t)idx * 12);
  o[0] = a0;
  o[1] = a1;
  o[2] = a2;
}

__global__ __launch_bounds__(256) void conv23_kernel(
    const float* __restrict__ x1, const float* __restrict__ w23,
    float* __restrict__ adj) {
  __shared__ float w[90];
  if (threadIdx.x < 90) w[threadIdx.x] = w23[threadIdx.x];
  __syncthreads();
  int idx = blockIdx.x * 256 + threadIdx.x;
  if (idx >= BDIM * NOBJ * NOBJ) return;
  int j = idx % NOBJ;
  int i = (idx / NOBJ) % NOBJ;
  int b = idx / (NOBJ * NOBJ);
  float acc = 0.f;
  const float* xb = x1 + (size_t)b * NOBJ * NOBJ * 12;
#pragma unroll
  for (int kh = 0; kh < 3; ++kh) {
    int ii = i + kh - 1;
    if (ii < 0 || ii >= NOBJ) continue;
#pragma unroll
    for (int kw = 0; kw < 3; ++kw) {
      int jj = j + kw - 1;
      if (jj < 0 || jj >= NOBJ) continue;
      const float* xr = xb + (ii * NOBJ + jj) * 12;
      const float* wr = w + (kh * 3 + kw) * 10;
#pragma unroll
      for (int c = 0; c < 10; ++c) acc += wr[c] * xr[c];
    }
  }
  adj[idx] = tanhf(acc);
}

// ---------------------------------------------------------------------------
// einsum via MFMA: ofl_u[b] = adj[b] (100x100) @ u1[b] (100x1024)
// (see R4 notes; swizzled LDS transpose-on-stage, K padded to 128, zeroed)
// ---------------------------------------------------------------------------
__global__ __launch_bounds__(256) void einsum_mfma_kernel(
    const float* __restrict__ adj,    // [32][100][100]
    const bf16_t* __restrict__ u1,    // [3200][1024]
    bf16_t* __restrict__ ofl) {       // [3200][1024]
  __shared__ __align__(16) bf16_t As[128 * 128];  // [n-row][k=m] swizzled
  __shared__ __align__(16) bf16_t Us[128 * 128];  // [h-col][k=m] swizzled
  const int b = blockIdx.y;
  const int h0 = blockIdx.x * 128;
  const int tid = threadIdx.x, lane = tid & 63, w = tid >> 6;
  const int wm = w >> 1, wn = w & 1;
  const int lr = lane & 15, lk = lane >> 4;

  {
    f32x4 z = {0.f, 0.f, 0.f, 0.f};
#pragma unroll
    for (int i = 0; i < 8; ++i) ((f32x4*)As)[tid + i * 256] = z;
#pragma unroll
    for (int i = 0; i < 8; ++i) ((f32x4*)Us)[tid + i * 256] = z;
  }
  __syncthreads();

  const float* ab = adj + (size_t)b * 10000;
#pragma unroll
  for (int i = 0; i < 10; ++i) {
    int idx = tid + i * 256;
    if (idx < 2500) {
      int row = idx / 25, kc = idx % 25;
      f32x4 v = ((const f32x4*)ab)[idx];
      bf16x4 o = {(bf16_t)v[0], (bf16_t)v[1], (bf16_t)v[2], (bf16_t)v[3]};
      int slot = kc >> 1;
      *(bf16x4*)((char*)As + row * 256 + ((slot ^ (row & 7)) << 4) +
                 (kc & 1) * 8) = o;
    }
  }

  const bf16_t* ub = u1 + (size_t)b * 100 * HDIM + h0;
#pragma unroll
  for (int i = 0; i < 7; ++i) {
    int idx = tid + i * 256;
    if (idx < 1600) {
      int hc = idx / 100, m = idx % 100;
      bf16x8 v = *(const bf16x8*)(ub + (size_t)m * HDIM + hc * 8);
      int slot = m >> 3, mr = m & 7;
#pragma unroll
      for (int j = 0; j < 8; ++j) {
        int h = hc * 8 + j;
        *((bf16_t*)((char*)Us + h * 256 + ((slot ^ (h & 7)) << 4) + mr * 2)) =
            v[j];
      }
    }
  }
  __syncthreads();

  f32x4 acc[4][4];
#pragma unroll
  for (int m = 0; m < 4; ++m)
#pragma unroll
    for (int n = 0; n < 4; ++n) acc[m][n] = (f32x4){0.f, 0.f, 0.f, 0.f};

#pragma unroll
  for (int ks = 0; ks < 4; ++ks) {
    bf16x8 a[4], u[4];
#pragma unroll
    for (int m = 0; m < 4; ++m) {
      int row = wm * 64 + m * 16 + lr;
      int slot = ks * 4 + lk;
      a[m] = *(const bf16x8*)((char*)As + row * 256 + ((slot ^ (lr & 7)) << 4));
    }
#pragma unroll
    for (int n = 0; n < 4; ++n) {
      int row = wn * 64 + n * 16 + lr;
      int slot = ks * 4 + lk;
      u[n] = *(const bf16x8*)((char*)Us + row * 256 + ((slot ^ (lr & 7)) << 4));
    }
#pragma unroll
    for (int m = 0; m < 4; ++m)
#pragma unroll
      for (int n = 0; n < 4; ++n)
        acc[m][n] = __builtin_amdgcn_mfma_f32_16x16x32_bf16(a[m], u[n],
                                                            acc[m][n], 0, 0, 0);
  }

  const int or0 = wm * 64 + lk * 4;
  const int oc0 = h0 + wn * 64 + lr;
#pragma unroll
  for (int m = 0; m < 4; ++m)
#pragma unroll
    for (int n = 0; n < 4; ++n)
#pragma unroll
      for (int r = 0; r < 4; ++r) {
        int row = or0 + m * 16 + r;
        if (row < 100)
          ofl[((size_t)b * 100 + row) * HDIM + oc0 + n * 16] =
              (bf16_t)acc[m][n][r];
      }
}

// ---------------------------------------------------------------------------
extern "C" void kernel_launch(void* const* d_in, const int* in_sizes, int n_in,
                              void* d_out, int out_size, void* d_ws,
                              size_t ws_size, hipStream_t stream) {
  const float* enc = (const float*)d_in[0];
  const float* W_comp = (const float*)d_in[1];
  const float* W_ou1 = (const float*)d_in[2];
  const float* W_ofc = (const float*)d_in[3];
  const float* W_dec = (const float*)d_in[4];
  const float* conv1w = (const float*)d_in[5];
  const float* conv2w = (const float*)d_in[6];
  const float* conv3w = (const float*)d_in[7];
  const float* femb = (const float*)d_in[8];
  const int* preds = (const int*)d_in[9];
  float* out = (float*)d_out;
  char* wsb = (char*)d_ws;

  const size_t MN = (size_t)TDIM * HDIM;  // 3,276,800

  // workspace (bytes), peak ~77.6MB (ws >= 112MB proven in R1).
  // encb LIVE until G4. part4 [41.16M,67.37M) dead after reduce4 (before
  // Wou1T/w1r/femb1/pidx/x1 writes, which overlay it). Phase-C buffers
  // overlay WcompT/comp/part4-head/femb1 (all dead by then); x1 (ends
  // 69.76M) stays clear of WdecT (ends 49.81M).
  bf16_t* encb   = (bf16_t*)(wsb + 0);           // 26,214,400 (LIVE to G4)
  bf16_t* WcompT = (bf16_t*)(wsb + 26214400);    //  8,388,608
  bf16_t* comp   = (bf16_t*)(wsb + 34603008);    //  6,553,600
  bf16_t* part4  = (bf16_t*)(wsb + 41156608);    // 26,214,400 (ends 67.37M)
  bf16_t* Wou1T  = (bf16_t*)(wsb + 41156608);    //  2,097,152 (after reduce4)
  float*  w1r    = (float*)(wsb + 43253760);     //     18,360
  float*  w23    = (float*)(wsb + 43272128);     //        360
  float*  femb1  = (float*)(wsb + 43272512);     //  9,850,032 (ends 53.12M)
  int*    pidx   = (int*)(wsb + 53122560);       //  1,280,000 (ends 54.40M)
  float*  x1     = (float*)(wsb + 54402560);     // 15,360,000 (ends 69.76M)
  bf16_t* obj_u1 = (bf16_t*)(wsb + 69762560);    //  6,553,600
  float*  adj    = (float*)(wsb + 76316160);     //  1,280,000 (ends 77.6M)
  // phase C
  bf16_t* ofl_u  = (bf16_t*)(wsb + 26214400);    //  6,553,600 (over WcompT)
  bf16_t* WofcT  = (bf16_t*)(wsb + 32768000);    //  2,097,152
  bf16_t* u_m    = (bf16_t*)(wsb + 34865152);    //  6,553,600 (ends 41.42M)
  bf16_t* WdecT  = (bf16_t*)(wsb + 41418752);    //  8,388,608 (ends 49.81M)

  const int n8 = (int)(MN / 8);  // 409,600 -> 1600 blocks for reduceN

  // --- conversions for GEMM1 ---
  cvt_bf16_kernel<<<(TDIM * DDIM / 4 + 255) / 256, 256, 0, stream>>>(
      enc, encb, TDIM * DDIM / 4);
  transT_kernel<<<dim3(HDIM / 32, DDIM / 32), 256, 0, stream>>>(
      W_comp, WcompT, DDIM, HDIM);

  // 1. comp = relu(enc @ W_comp)  M=3200 N=1024 K=4096
  //    split-K=4, MODE3: XCD-pair K-planes + L2 chunking (832 blocks)
  gemm_bf16<false, false, 4, 3><<<dim3(832, 1, 1), 256, 0, stream>>>(
      encb, WcompT, nullptr, part4, HDIM, DDIM, MN);
  reduceN_kernel<4><<<n8 / 256, 256, 0, stream>>>(part4, comp, n8, MN);

  // 2. obj_u1 = relu(comp @ W_ou1) M=3200 N=1024 K=1024
  transT_kernel<<<dim3(HDIM / 32, HDIM / 32), 256, 0, stream>>>(
      W_ou1, Wou1T, HDIM, HDIM);
  gemm_bf16<true, false, 1, 0>
      <<<dim3(HDIM / 128, TDIM / 128), 256, 0, stream>>>(
          comp, Wou1T, nullptr, obj_u1, HDIM, HDIM, MN);

  // 3. conv chain precomputes
  prep_w1r_kernel<<<(NRCH * 90 + 255) / 256, 256, 0, stream>>>(conv1w, w1r);
  prep_w23_kernel<<<1, 128, 0, stream>>>(conv2w, conv3w, w23);
  pidx_kernel<<<(BDIM * NOBJ * NOBJ + 255) / 256, 256, 0, stream>>>(preds,
                                                                    pidx);
  femb1_kernel<<<NCC * NCC, 128, 0, stream>>>(femb, w1r, femb1);

  // 4. conv1 via gather-sum; 5. conv2+conv3+tanh fused
  conv1g_kernel<<<(BDIM * NOBJ * NOBJ + 255) / 256, 256, 0, stream>>>(
      pidx, femb1, x1);
  conv23_kernel<<<(BDIM * NOBJ * NOBJ + 255) / 256, 256, 0, stream>>>(x1, w23,
                                                                      adj);

  // conversions for GEMM3/4
  transT_kernel<<<dim3(HDIM / 32, HDIM / 32), 256, 0, stream>>>(
      W_ofc, WofcT, HDIM, HDIM);
  transT_kernel<<<dim3(DDIM / 32, HDIM / 32), 256, 0, stream>>>(
      W_dec, WdecT, HDIM, DDIM);

  // 7. einsum via MFMA -> ofl_u (bf16)
  einsum_mfma_kernel<<<dim3(HDIM / 128, BDIM), 256, 0, stream>>>(adj, obj_u1,
                                                                 ofl_u);

  // 8. u_m = relu(ofl_u @ W_ofc)  M=3200 N=1024 K=1024
  gemm_bf16<true, false, 1, 0>
      <<<dim3(HDIM / 128, TDIM / 128), 256, 0, stream>>>(
          ofl_u, WofcT, nullptr, u_m, HDIM, HDIM, MN);

  // 9. out = relu(u_m @ W_dec) + enc(bf16)  M=3200 N=4096 K=1024 (fp32 out)
  gemm_bf16<true, true, 1, 0>
      <<<dim3(DDIM / 128, TDIM / 128), 256, 0, stream>>>(
          u_m, WdecT, encb, out, DDIM, HDIM, MN);
}